// Round 18
// baseline (370.593 us; speedup 1.0000x reference)
//
#include <hip/hip_runtime.h>
#include <hip/hip_bf16.h>

#define EPS   1e-5f
#define NH    4      // heads
#define DIN   128
#define DHID  64
#define DOUT  32
#define PNODES 256   // nodes per k_pool block
#define CAP   128    // per-wave LDS edge capacity in k_agg
#define GM    32     // rows per MFMA gemm block
#define NBUCK 64     // partition buckets (dst >> bshift)
#define BSTR  16     // bcur stride (ints) = one 64B line per bucket
#define EPB   1024   // edges per k_part block

typedef __attribute__((ext_vector_type(8))) short short8;   // 8 bf16 (4 VGPRs)
typedef __attribute__((ext_vector_type(4))) float f32x4;    // MFMA accumulator
typedef __attribute__((ext_vector_type(2))) float f32x2;    // fp8 cvt result

__device__ __forceinline__ float us2f(unsigned short u) {   // raw bf16 bits -> f32
    return __uint_as_float((unsigned)u << 16);
}
__device__ __forceinline__ unsigned short f2us(float v) {   // f32 -> bf16 bits (RN)
    __hip_bfloat16 hb = __float2bfloat16(v);
    return *(unsigned short*)&hb;
}
__device__ __forceinline__ unsigned char f2e4m3(float v) {  // f32 -> fp8 e4m3 (HW, OCP)
    int p = __builtin_amdgcn_cvt_pk_fp8_f32(v, 0.f, 0, false);
    return (unsigned char)(p & 0xff);
}
__device__ __forceinline__ float lrelu(float a) { return (a >= 0.f) ? a : 0.2f * a; }

// ---------------------------------------------------------------- init: deg=1 (self-loop), zero pool/cnt/bcur
__global__ void k_init0(int* __restrict__ deg, float* __restrict__ pool,
                        int* __restrict__ bcur, int N, int npool) {
    int g = blockIdx.x * blockDim.x + threadIdx.x;
    if (g < N) deg[g] = 1;
    if (g < npool) pool[g] = 0.f;
    if (g < NBUCK * BSTR) bcur[g] = 0;
}

// ---------------------------------------------------------------- 3-phase parallel exclusive scan
__global__ __launch_bounds__(256) void k_scan_a(const int* __restrict__ deg,
                                                int* __restrict__ rowptr,
                                                int* __restrict__ bsum, int N) {
    __shared__ int sh[256];
    const int t = threadIdx.x;
    const int i = blockIdx.x * 256 + t;
    int v = (i < N) ? deg[i] : 0;
    sh[t] = v;
    __syncthreads();
    #pragma unroll
    for (int o = 1; o < 256; o <<= 1) {
        int u = (t >= o) ? sh[t - o] : 0;
        __syncthreads();
        sh[t] += u;
        __syncthreads();
    }
    if (i < N) rowptr[i] = sh[t] - v;
    if (t == 255) bsum[blockIdx.x] = sh[255];
}

__global__ __launch_bounds__(256) void k_scan_b(int* __restrict__ bsum, int nb) {
    __shared__ int sh[256];
    const int t = threadIdx.x;
    int v = (t < nb) ? bsum[t] : 0;
    sh[t] = v;
    __syncthreads();
    #pragma unroll
    for (int o = 1; o < 256; o <<= 1) {
        int u = (t >= o) ? sh[t - o] : 0;
        __syncthreads();
        sh[t] += u;
        __syncthreads();
    }
    if (t < nb) bsum[t] = sh[t] - v;
}

__global__ __launch_bounds__(256) void k_scan_c(int* __restrict__ rowptr,
                                                int* __restrict__ cursor,
                                                const int* __restrict__ bsum,
                                                int N, int Etot) {
    const int i = blockIdx.x * 256 + threadIdx.x;
    if (i < N) {
        int v = rowptr[i] + bsum[blockIdx.x];
        rowptr[i] = v;
        cursor[i] = v;
    }
    if (i == 0) rowptr[N] = Etot;
}

// ---------------------------------------------------------------- CSR fill phase A: bucket partition + deg hist
// bcur padded to one 64B line per bucket; lhist stride-2 to halve LDS bank collisions
__global__ __launch_bounds__(256) void k_part(
    const int* __restrict__ ei, int E, int N, int bshift,
    unsigned long long* __restrict__ arena, int* __restrict__ bcur,
    int* __restrict__ deg, int cap)
{
    __shared__ int lhist[NBUCK * 2];
    __shared__ int lbase[NBUCK];
    const int t = threadIdx.x;
    const int e0 = blockIdx.x * EPB;
    const int eEnd = min(e0 + EPB, E + N);

    if (t < NBUCK) lhist[t * 2] = 0;
    __syncthreads();

    int myb[4], myd[4], mys[4];
    #pragma unroll
    for (int r = 0; r < 4; ++r) {
        int e = e0 + r * 256 + t;
        myb[r] = -1;
        if (e < eEnd) {
            int s, d;
            if (e < E) { s = ei[e]; d = ei[E + e]; atomicAdd(&deg[d], 1); }
            else       { s = d = e - E; }          // self-loop: deg pre-set to 1 in init
            int b = d >> bshift;
            myb[r] = b; myd[r] = d; mys[r] = s;
            atomicAdd(&lhist[b * 2], 1);
        }
    }
    __syncthreads();

    if (t < NBUCK) {
        int c = lhist[t * 2];
        lbase[t] = c ? atomicAdd(&bcur[t * BSTR], c) : 0;   // one line per bucket
        lhist[t * 2] = 0;     // reuse as local bump
    }
    __syncthreads();

    #pragma unroll
    for (int r = 0; r < 4; ++r) {
        int b = myb[r];
        if (b >= 0) {
            int li = atomicAdd(&lhist[b * 2], 1);
            int pos = lbase[b] + li;
            if (pos >= cap) pos = cap - 1;    // safety (statistically unreachable)
            arena[(size_t)b * cap + pos] =
                ((unsigned long long)(unsigned)myd[r] << 32) | (unsigned)mys[r];
        }
    }
}

// ---------------------------------------------------------------- CSR fill phase B: bucket-local scatter
__global__ __launch_bounds__(256) void k_fill2(
    const unsigned long long* __restrict__ arena, const int* __restrict__ bcur,
    int cap, int* __restrict__ cursor, int* __restrict__ col)
{
    const int b = blockIdx.x;
    const int idx = blockIdx.y * 256 + threadIdx.x;
    if (idx >= bcur[b * BSTR]) return;
    unsigned long long v = arena[(size_t)b * cap + idx];
    int d = (int)(v >> 32);
    int s = (int)(v & 0xffffffffu);
    int pos = atomicAdd(&cursor[d], 1);
    col[pos] = s;
}

// ---------------------------------------------------------------- prep:
// BN(x)->bf16 A; W1^T->Wt; W2^T->Wt2; folded attention mats Wast1[16][128], Wast2[16][64];
// BN1 scale/shift
__global__ __launch_bounds__(256) void k_prep(
    const float* __restrict__ x,
    const float* __restrict__ ing, const float* __restrict__ inb,
    const float* __restrict__ inm, const float* __restrict__ inv,
    const float* __restrict__ W1, const float* __restrict__ W2,
    const float* __restrict__ as1, const float* __restrict__ ad1,
    const float* __restrict__ as2, const float* __restrict__ ad2,
    const float* __restrict__ b1,
    const float* __restrict__ bn1g, const float* __restrict__ bn1b,
    const float* __restrict__ bn1m, const float* __restrict__ bn1v,
    unsigned short* __restrict__ A, unsigned short* __restrict__ Wt,
    unsigned short* __restrict__ Wt2,
    unsigned short* __restrict__ Wast1, unsigned short* __restrict__ Wast2,
    float* __restrict__ scl1, float* __restrict__ shf1, int N)
{
    int g = blockIdx.x * blockDim.x + threadIdx.x;
    int totA = N * (DIN / 4);
    if (g < totA) {
        int n = g >> 5, k4 = (g & 31) * 4;
        float4 xv = *(const float4*)(x + (size_t)n * DIN + k4);
        float4 gm = *(const float4*)(ing + k4);
        float4 bb = *(const float4*)(inb + k4);
        float4 mm = *(const float4*)(inm + k4);
        float4 vv = *(const float4*)(inv + k4);
        ushort4 o;
        o.x = f2us((xv.x - mm.x) * rsqrtf(vv.x + EPS) * gm.x + bb.x);
        o.y = f2us((xv.y - mm.y) * rsqrtf(vv.y + EPS) * gm.y + bb.y);
        o.z = f2us((xv.z - mm.z) * rsqrtf(vv.z + EPS) * gm.z + bb.z);
        o.w = f2us((xv.w - mm.w) * rsqrtf(vv.w + EPS) * gm.w + bb.w);
        *(ushort4*)(A + (size_t)n * DIN + k4) = o;
    }
    if (g < 256 * DIN) {   // Wt[n][k] = W1[k][n]
        int n = g >> 7, k = g & 127;
        Wt[g] = f2us(W1[(size_t)k * 256 + n]);
    }
    if (g < 256 * DHID) {  // Wt2[n][k] = W2[k][n]
        int n = g >> 6, k = g & 63;
        Wt2[g] = f2us(W2[(size_t)k * 256 + n]);
    }
    if (g < 16 * DIN) {    // Wast1[c][k]: c<4 -> W1·as1 head c ; 4..7 -> W1·ad1 ; 8..15 -> 0
        int c = g >> 7, k = g & 127;
        float s = 0.f;
        if (c < 4)      { for (int j = 0; j < 64; ++j) s += W1[(size_t)k * 256 + c * 64 + j] * as1[c * 64 + j]; }
        else if (c < 8) { for (int j = 0; j < 64; ++j) s += W1[(size_t)k * 256 + (c - 4) * 64 + j] * ad1[(c - 4) * 64 + j]; }
        Wast1[g] = f2us(s);
    }
    if (g < 16 * DHID) {   // Wast2[c][k]
        int c = g >> 6, k = g & 63;
        float s = 0.f;
        if (c < 4)      { for (int j = 0; j < 64; ++j) s += W2[(size_t)k * 256 + c * 64 + j] * as2[c * 64 + j]; }
        else if (c < 8) { for (int j = 0; j < 64; ++j) s += W2[(size_t)k * 256 + (c - 4) * 64 + j] * ad2[(c - 4) * 64 + j]; }
        Wast2[g] = f2us(s);
    }
    if (g < DHID) {        // fold b1 + BN1 into scale/shift
        float sc = bn1g[g] * rsqrtf(bn1v[g] + EPS);
        scl1[g] = sc;
        shf1[g] = (b1[g] - bn1m[g]) * sc + bn1b[g];
    }
}

// ---------------------------------------------------------------- layer-1 GEMM via MFMA (h fp8 + fused att)
__global__ __launch_bounds__(256) void k_gemm1(
    const unsigned short* __restrict__ A,    // [N][128] bf16
    const unsigned short* __restrict__ Wt,   // [256][128] bf16
    const unsigned short* __restrict__ Wast, // [16][128] bf16 (cols 8..15 zero)
    unsigned char* __restrict__ h,           // [N][256] fp8 (transposed [n][c][hd])
    float* __restrict__ asrc, float* __restrict__ adst, int N)
{
    __shared__ float Csh[GM][260];
    const int t = threadIdx.x;
    const int lane = t & 63, wv = t >> 6;
    const int qm = lane & 15, qd = lane >> 4;
    const int base = blockIdx.x * GM;

    short8 afr[2][4];
    #pragma unroll
    for (int rt = 0; rt < 2; ++rt) {
        int node = base + rt * 16 + qm;
        if (node >= N) node = N - 1;
        const unsigned short* ap = A + (size_t)node * DIN + qd * 8;
        #pragma unroll
        for (int ks = 0; ks < 4; ++ks)
            afr[rt][ks] = *(const short8*)(ap + ks * 32);
    }

    const int n0 = wv * 64;
    f32x4 acc[2][4];
    #pragma unroll
    for (int rt = 0; rt < 2; ++rt)
        #pragma unroll
        for (int ct = 0; ct < 4; ++ct)
            acc[rt][ct] = (f32x4){0.f, 0.f, 0.f, 0.f};

    #pragma unroll
    for (int ct = 0; ct < 4; ++ct) {
        const unsigned short* bp = Wt + (size_t)(n0 + ct * 16 + qm) * DIN + qd * 8;
        #pragma unroll
        for (int ks = 0; ks < 4; ++ks) {
            short8 bfr = *(const short8*)(bp + ks * 32);
            acc[0][ct] = __builtin_amdgcn_mfma_f32_16x16x32_bf16(afr[0][ks], bfr, acc[0][ct], 0, 0, 0);
            acc[1][ct] = __builtin_amdgcn_mfma_f32_16x16x32_bf16(afr[1][ks], bfr, acc[1][ct], 0, 0, 0);
        }
    }

    // fused attention logits: [asrc|adst] = A @ Wast^T (reuses afr)
    {
        const unsigned short* wp = Wast + (size_t)qm * DIN + qd * 8;
        f32x4 aat[2];
        aat[0] = (f32x4){0.f, 0.f, 0.f, 0.f};
        aat[1] = (f32x4){0.f, 0.f, 0.f, 0.f};
        #pragma unroll
        for (int ks = 0; ks < 4; ++ks) {
            short8 wfr = *(const short8*)(wp + ks * 32);
            aat[0] = __builtin_amdgcn_mfma_f32_16x16x32_bf16(afr[0][ks], wfr, aat[0], 0, 0, 0);
            aat[1] = __builtin_amdgcn_mfma_f32_16x16x32_bf16(afr[1][ks], wfr, aat[1], 0, 0, 0);
        }
        const int c = qm;   // C layout: col = lane&15, row = qd*4+rg
        #pragma unroll
        for (int rt = 0; rt < 2; ++rt)
            #pragma unroll
            for (int rg = 0; rg < 4; ++rg) {
                int nd = base + rt * 16 + qd * 4 + rg;
                if (nd < N) {
                    if (c < 4)      asrc[nd * 4 + c] = aat[rt][rg];
                    else if (c < 8) adst[nd * 4 + (c - 4)] = aat[rt][rg];
                }
            }
    }

    #pragma unroll
    for (int rt = 0; rt < 2; ++rt)
        #pragma unroll
        for (int ct = 0; ct < 4; ++ct)
            #pragma unroll
            for (int rg = 0; rg < 4; ++rg)
                Csh[rt * 16 + qd * 4 + rg][n0 + ct * 16 + qm] = acc[rt][ct][rg];
    __syncthreads();

    const int hcol = ((t & 3) << 6) | (t >> 2);   // h[n][t] <- C[n][(t&3)*64 + (t>>2)]
    for (int r = 0; r < GM; ++r) {
        int node = base + r;
        if (node >= N) break;
        h[(size_t)node * 256 + t] = f2e4m3(Csh[r][hcol]);
    }
}

// ---------------------------------------------------------------- layer-2 GEMM via MFMA (K=64, h fp8 + fused att)
__global__ __launch_bounds__(256) void k_gemm2(
    const unsigned short* __restrict__ A2,   // [N][64] bf16
    const unsigned short* __restrict__ Wt2,  // [256][64] bf16
    const unsigned short* __restrict__ Wast, // [16][64] bf16
    unsigned char* __restrict__ h,
    float* __restrict__ asrc, float* __restrict__ adst, int N)
{
    __shared__ float Csh[GM][260];
    const int t = threadIdx.x;
    const int lane = t & 63, wv = t >> 6;
    const int qm = lane & 15, qd = lane >> 4;
    const int base = blockIdx.x * GM;

    short8 afr[2][2];
    #pragma unroll
    for (int rt = 0; rt < 2; ++rt) {
        int node = base + rt * 16 + qm;
        if (node >= N) node = N - 1;
        const unsigned short* ap = A2 + (size_t)node * DHID + qd * 8;
        #pragma unroll
        for (int ks = 0; ks < 2; ++ks)
            afr[rt][ks] = *(const short8*)(ap + ks * 32);
    }

    const int n0 = wv * 64;
    f32x4 acc[2][4];
    #pragma unroll
    for (int rt = 0; rt < 2; ++rt)
        #pragma unroll
        for (int ct = 0; ct < 4; ++ct)
            acc[rt][ct] = (f32x4){0.f, 0.f, 0.f, 0.f};

    #pragma unroll
    for (int ct = 0; ct < 4; ++ct) {
        const unsigned short* bp = Wt2 + (size_t)(n0 + ct * 16 + qm) * DHID + qd * 8;
        #pragma unroll
        for (int ks = 0; ks < 2; ++ks) {
            short8 bfr = *(const short8*)(bp + ks * 32);
            acc[0][ct] = __builtin_amdgcn_mfma_f32_16x16x32_bf16(afr[0][ks], bfr, acc[0][ct], 0, 0, 0);
            acc[1][ct] = __builtin_amdgcn_mfma_f32_16x16x32_bf16(afr[1][ks], bfr, acc[1][ct], 0, 0, 0);
        }
    }

    // fused attention logits
    {
        const unsigned short* wp = Wast + (size_t)qm * DHID + qd * 8;
        f32x4 aat[2];
        aat[0] = (f32x4){0.f, 0.f, 0.f, 0.f};
        aat[1] = (f32x4){0.f, 0.f, 0.f, 0.f};
        #pragma unroll
        for (int ks = 0; ks < 2; ++ks) {
            short8 wfr = *(const short8*)(wp + ks * 32);
            aat[0] = __builtin_amdgcn_mfma_f32_16x16x32_bf16(afr[0][ks], wfr, aat[0], 0, 0, 0);
            aat[1] = __builtin_amdgcn_mfma_f32_16x16x32_bf16(afr[1][ks], wfr, aat[1], 0, 0, 0);
        }
        const int c = qm;
        #pragma unroll
        for (int rt = 0; rt < 2; ++rt)
            #pragma unroll
            for (int rg = 0; rg < 4; ++rg) {
                int nd = base + rt * 16 + qd * 4 + rg;
                if (nd < N) {
                    if (c < 4)      asrc[nd * 4 + c] = aat[rt][rg];
                    else if (c < 8) adst[nd * 4 + (c - 4)] = aat[rt][rg];
                }
            }
    }

    #pragma unroll
    for (int rt = 0; rt < 2; ++rt)
        #pragma unroll
        for (int ct = 0; ct < 4; ++ct)
            #pragma unroll
            for (int rg = 0; rg < 4; ++rg)
                Csh[rt * 16 + qd * 4 + rg][n0 + ct * 16 + qm] = acc[rt][ct][rg];
    __syncthreads();

    const int hcol = ((t & 3) << 6) | (t >> 2);
    for (int r = 0; r < GM; ++r) {
        int node = base + r;
        if (node >= N) break;
        h[(size_t)node * 256 + t] = f2e4m3(Csh[r][hcol]);
    }
}

// ---------------------------------------------------------------- pull-style GAT aggregation (fp8 h)
__global__ __launch_bounds__(256) void k_agg(
    const int* __restrict__ rowptr, const int* __restrict__ col,
    const float* __restrict__ asrc, const float* __restrict__ adst,
    const unsigned char* __restrict__ h8,
    float* __restrict__ outf, unsigned short* __restrict__ outb,
    const float* __restrict__ scl, const float* __restrict__ shf,
    int mode, int N)
{
    __shared__ float4 exs[4][CAP];
    __shared__ int    cols[4][CAP];
    const int lane = threadIdx.x & 63;
    const int wv   = threadIdx.x >> 6;
    const int d = (blockIdx.x << 2) + wv;
    if (d >= N) return;
    const int r0  = rowptr[d];
    const int deg = rowptr[d + 1] - r0;        // >= 1 (self-loop)

    const float4 ad4 = ((const float4*)adst)[d];
    const float4* __restrict__ as4 = (const float4*)asrc;

    // pass A: exp(lrelu(logit)) -> LDS, per-head sum
    float sm0 = 0.f, sm1 = 0.f, sm2 = 0.f, sm3 = 0.f;
    for (int j = lane; j < deg; j += 64) {
        int s = col[r0 + j];
        float4 a = as4[s];
        float e0 = __expf(lrelu(a.x + ad4.x));
        float e1 = __expf(lrelu(a.y + ad4.y));
        float e2 = __expf(lrelu(a.z + ad4.z));
        float e3 = __expf(lrelu(a.w + ad4.w));
        if (j < CAP) { cols[wv][j] = s; exs[wv][j] = make_float4(e0, e1, e2, e3); }
        sm0 += e0; sm1 += e1; sm2 += e2; sm3 += e3;
    }
    #pragma unroll
    for (int o = 1; o < 64; o <<= 1) {
        sm0 += __shfl_xor(sm0, o, 64);
        sm1 += __shfl_xor(sm1, o, 64);
        sm2 += __shfl_xor(sm2, o, 64);
        sm3 += __shfl_xor(sm3, o, 64);
    }
    const float i0 = 0.25f / sm0, i1 = 0.25f / sm1, i2 = 0.25f / sm2, i3 = 0.25f / sm3;

    // pass B: lane = channel; 4 independent dword gathers per iteration
    const unsigned int* __restrict__ hu = (const unsigned int*)h8;
    float a0 = 0.f, a1 = 0.f, a2 = 0.f, a3 = 0.f;
    float b0 = 0.f, b1 = 0.f, b2 = 0.f, b3 = 0.f;
    if (deg <= CAP) {
        int j = 0;
        for (; j + 3 < deg; j += 4) {
            int sA = cols[wv][j],     sB = cols[wv][j + 1];
            int sC = cols[wv][j + 2], sD = cols[wv][j + 3];
            unsigned int vA = hu[(size_t)sA * 64 + lane];
            unsigned int vB = hu[(size_t)sB * 64 + lane];
            unsigned int vC = hu[(size_t)sC * 64 + lane];
            unsigned int vD = hu[(size_t)sD * 64 + lane];
            float4 wA = exs[wv][j],     wB = exs[wv][j + 1];
            float4 wC = exs[wv][j + 2], wD = exs[wv][j + 3];
            f32x2 lA = __builtin_amdgcn_cvt_pk_f32_fp8(vA, false), hA = __builtin_amdgcn_cvt_pk_f32_fp8(vA, true);
            f32x2 lB = __builtin_amdgcn_cvt_pk_f32_fp8(vB, false), hB = __builtin_amdgcn_cvt_pk_f32_fp8(vB, true);
            f32x2 lC = __builtin_amdgcn_cvt_pk_f32_fp8(vC, false), hC = __builtin_amdgcn_cvt_pk_f32_fp8(vC, true);
            f32x2 lD = __builtin_amdgcn_cvt_pk_f32_fp8(vD, false), hD = __builtin_amdgcn_cvt_pk_f32_fp8(vD, true);
            a0 += wA.x * lA.x; a1 += wA.y * lA.y; a2 += wA.z * hA.x; a3 += wA.w * hA.y;
            b0 += wB.x * lB.x; b1 += wB.y * lB.y; b2 += wB.z * hB.x; b3 += wB.w * hB.y;
            a0 += wC.x * lC.x; a1 += wC.y * lC.y; a2 += wC.z * hC.x; a3 += wC.w * hC.y;
            b0 += wD.x * lD.x; b1 += wD.y * lD.y; b2 += wD.z * hD.x; b3 += wD.w * hD.y;
        }
        for (; j < deg; ++j) {
            int s = cols[wv][j];
            unsigned int v = hu[(size_t)s * 64 + lane];
            float4 w = exs[wv][j];
            f32x2 lo = __builtin_amdgcn_cvt_pk_f32_fp8(v, false), hi = __builtin_amdgcn_cvt_pk_f32_fp8(v, true);
            a0 += w.x * lo.x; a1 += w.y * lo.y; a2 += w.z * hi.x; a3 += w.w * hi.y;
        }
    } else {                                     // rare: deg > CAP, recompute weights
        for (int j = 0; j < deg; ++j) {
            int s; float4 w;
            if (j < CAP) { s = cols[wv][j]; w = exs[wv][j]; }
            else {
                s = col[r0 + j];
                float4 a = as4[s];
                w.x = __expf(lrelu(a.x + ad4.x)); w.y = __expf(lrelu(a.y + ad4.y));
                w.z = __expf(lrelu(a.z + ad4.z)); w.w = __expf(lrelu(a.w + ad4.w));
            }
            unsigned int v = hu[(size_t)s * 64 + lane];
            f32x2 lo = __builtin_amdgcn_cvt_pk_f32_fp8(v, false), hi = __builtin_amdgcn_cvt_pk_f32_fp8(v, true);
            a0 += w.x * lo.x; a1 += w.y * lo.y; a2 += w.z * hi.x; a3 += w.w * hi.y;
        }
    }
    float acc = (a0 + b0) * i0 + (a1 + b1) * i1 + (a2 + b2) * i2 + (a3 + b3) * i3;

    if (mode) {
        float v = fmaxf(acc * scl[lane] + shf[lane], 0.f);
        outb[(size_t)d * 64 + lane] = f2us(v);
    } else {
        outf[(size_t)d * 64 + lane] = acc;
    }
}

// ---------------------------------------------------------------- pool (unchanged)
__global__ __launch_bounds__(256) void k_pool(
    const float* __restrict__ outacc,
    const float* __restrict__ b2_,
    const float* __restrict__ bg, const float* __restrict__ bb,
    const float* __restrict__ bm, const float* __restrict__ bv,
    const int* __restrict__ batch,
    float* __restrict__ pool, float* __restrict__ cnt, int N)
{
    const int lane = threadIdx.x & 63;
    const int wave = threadIdx.x >> 6;
    const int base = blockIdx.x * PNODES;
    int end = base + PNODES; if (end > N) end = N;

    const float scale = bg[lane] * rsqrtf(bv[lane] + EPS);
    const float shift = (b2_[lane] - bm[lane]) * scale + bb[lane];

    float acc = 0.f;
    int cur = -1, cl = 0;
    for (int n = base + wave; n < end; n += 4) {
        int gr = batch[n];
        if (gr != cur) {
            if (cur >= 0) {
                atomicAdd(&pool[cur * 64 + lane], acc);
                if (lane == 0) atomicAdd(&cnt[cur], (float)cl);
            }
            cur = gr; acc = 0.f; cl = 0;
        }
        float v = fmaxf(outacc[(size_t)n * 64 + lane] * scale + shift, 0.f);
        acc += v; ++cl;
    }
    if (cur >= 0) {
        atomicAdd(&pool[cur * 64 + lane], acc);
        if (lane == 0) atomicAdd(&cnt[cur], (float)cl);
    }
}

// ---------------------------------------------------------------- head (unchanged)
__global__ void k_head(const float* __restrict__ pool, const float* __restrict__ cnt,
                       const float* __restrict__ fc1w, const float* __restrict__ fc1b,
                       const float* __restrict__ fc2w, const float* __restrict__ fc2b,
                       float* __restrict__ out)
{
    int g = blockIdx.x;
    int t = threadIdx.x;  // 64 threads
    __shared__ float emb[64];
    __shared__ float z1[32];
    float c = fmaxf(cnt[g], 1.0f);
    emb[t] = pool[g * 64 + t] / c;
    __syncthreads();
    if (t < 32) {
        float s = fc1b[t];
        for (int k = 0; k < 64; ++k) s += emb[k] * fc1w[k * 32 + t];
        z1[t] = fmaxf(s, 0.f);
    }
    __syncthreads();
    if (t < 32) {
        float o = fc2b[t];
        for (int j = 0; j < 32; ++j) o += z1[j] * fc2w[j * 32 + t];
        out[g * 32 + t] = o;
    }
}

// ---------------------------------------------------------------- launch
extern "C" void kernel_launch(void* const* d_in, const int* in_sizes, int n_in,
                              void* d_out, int out_size, void* d_ws, size_t ws_size,
                              hipStream_t stream)
{
    const float* x    = (const float*)d_in[0];
    const int*   ei   = (const int*)d_in[1];
    const int*   batch= (const int*)d_in[2];
    const float* ing  = (const float*)d_in[3];
    const float* inb  = (const float*)d_in[4];
    const float* inm  = (const float*)d_in[5];
    const float* inv  = (const float*)d_in[6];
    const float* W1   = (const float*)d_in[7];
    const float* as1  = (const float*)d_in[8];
    const float* ad1  = (const float*)d_in[9];
    const float* b1   = (const float*)d_in[10];
    const float* bn1g = (const float*)d_in[11];
    const float* bn1b = (const float*)d_in[12];
    const float* bn1m = (const float*)d_in[13];
    const float* bn1v = (const float*)d_in[14];
    const float* W2   = (const float*)d_in[15];
    const float* as2  = (const float*)d_in[16];
    const float* ad2  = (const float*)d_in[17];
    const float* b2   = (const float*)d_in[18];
    const float* bn2g = (const float*)d_in[19];
    const float* bn2b = (const float*)d_in[20];
    const float* bn2m = (const float*)d_in[21];
    const float* bn2v = (const float*)d_in[22];
    const float* fc1w = (const float*)d_in[23];
    const float* fc1b = (const float*)d_in[24];
    const float* fc2w = (const float*)d_in[25];
    const float* fc2b = (const float*)d_in[26];

    const int N = in_sizes[0] / DIN;
    const int E = in_sizes[1] / 2;
    const int G = out_size / DOUT;
    const int Etot = E + N;

    // bucket shift: smallest with (N-1)>>bshift < NBUCK
    int bshift = 0;
    while ((N >> bshift) >= NBUCK) ++bshift;
    // per-bucket arena capacity: expected density * 1.25 + slack
    const int cap = (int)(((long long)Etot << bshift) / N * 5 / 4) + 512;

    // workspace layout — ~43 MB
    unsigned char* h8 = (unsigned char*)d_ws;             // N*256 fp8 (transposed [n][c][hd])
    float* asrc   = (float*)(h8 + (size_t)N * 256);       // N*4
    float* adst   = asrc + (size_t)N * NH;                // N*4
    unsigned short* Wt    = (unsigned short*)(adst + (size_t)N * NH); // 256*128
    unsigned short* Wt2   = Wt + 256 * DIN;               // 256*64
    unsigned short* Wast1 = Wt2 + 256 * DHID;             // 16*128
    unsigned short* Wast2 = Wast1 + 16 * DIN;             // 16*64
    float* scl1   = (float*)(Wast2 + 16 * DHID);          // 64
    float* shf1   = scl1 + DHID;                          // 64
    float* outacc = shf1 + DHID;                          // N*64 f32
    unsigned short* A  = (unsigned short*)outacc;         // alias: N*128 bf16 (dead after gemm1)
    unsigned short* A2 = (unsigned short*)outacc;         // alias: N*64 bf16 (layer-1 agg out)
    int*   deg    = (int*)(outacc + (size_t)N * DHID);    // N
    int*   rowptr = deg + N;                              // N+1
    int*   cursor = rowptr + N + 1;                       // N
    int*   col    = cursor + N;                           // E+N
    float* pool   = (float*)(col + Etot);                 // G*64
    float* cnt    = pool + (size_t)G * DHID;              // G
    int*   bsum   = (int*)(cnt + G);                      // <=256
    int*   bcur   = (int*)(((size_t)(bsum + 256) + 63) & ~(size_t)63); // NBUCK*BSTR (line-padded)
    unsigned long long* arena =
        (unsigned long long*)(((size_t)(bcur + NBUCK * BSTR) + 7) & ~(size_t)7); // NBUCK*cap*8B

    const int npool = G * DHID + G;
    const int nScanBlk = (N + 255) / 256;
    dim3 b256(256);

    // ---- CSR build (deg-hist fused into k_part) + zero pool/cnt/bcur
    k_init0<<<(N + 255) / 256, b256, 0, stream>>>(deg, pool, bcur, N, npool);
    k_part<<<(Etot + EPB - 1) / EPB, b256, 0, stream>>>(ei, E, N, bshift, arena, bcur, deg, cap);
    k_scan_a<<<nScanBlk, b256, 0, stream>>>(deg, rowptr, bsum, N);
    k_scan_b<<<1, b256, 0, stream>>>(bsum, nScanBlk);
    k_scan_c<<<nScanBlk, b256, 0, stream>>>(rowptr, cursor, bsum, N, Etot);
    {
        dim3 gFill(NBUCK, (cap + 255) / 256);
        k_fill2<<<gFill, b256, 0, stream>>>(arena, bcur, cap, cursor, col);
    }

    // ---- prep (BN+cast x, transpose W1/W2, fold attention mats, BN1 fold)
    const int prepThreads = N * (DIN / 4);
    k_prep<<<(prepThreads + 255) / 256, b256, 0, stream>>>(
        x, ing, inb, inm, inv, W1, W2, as1, ad1, as2, ad2,
        b1, bn1g, bn1b, bn1m, bn1v,
        A, Wt, Wt2, Wast1, Wast2, scl1, shf1, N);

    // ---- layer 1 (MFMA, fused att); agg writes bf16 A2 (bias+BN1+ReLU fused)
    k_gemm1<<<(N + GM - 1) / GM, b256, 0, stream>>>(A, Wt, Wast1, h8, asrc, adst, N);
    k_agg<<<(N + 3) / 4, b256, 0, stream>>>(rowptr, col, asrc, adst, h8,
                                            (float*)nullptr, A2, scl1, shf1, 1, N);

    // ---- layer 2 (MFMA, fused att); agg writes raw f32 for pool
    k_gemm2<<<(N + GM - 1) / GM, b256, 0, stream>>>(A2, Wt2, Wast2, h8, asrc, adst, N);
    k_agg<<<(N + 3) / 4, b256, 0, stream>>>(rowptr, col, asrc, adst, h8,
                                            outacc, (unsigned short*)nullptr,
                                            (const float*)nullptr, (const float*)nullptr, 0, N);

    // ---- pool + head
    k_pool<<<(N + PNODES - 1) / PNODES, b256, 0, stream>>>(outacc, b2, bn2g, bn2b, bn2m, bn2v,
                                                           batch, pool, cnt, N);
    k_head<<<G, 64, 0, stream>>>(pool, cnt, fc1w, fc1b, fc2w, fc2b, (float*)d_out);
}

// Round 19
// 356.002 us; speedup vs baseline: 1.0410x; 1.0410x over previous
//
#include <hip/hip_runtime.h>
#include <hip/hip_bf16.h>

#define EPS   1e-5f
#define NH    4      // heads
#define DIN   128
#define DHID  64
#define DOUT  32
#define PNODES 256   // nodes per k_pool block
#define CAP   128    // per-wave LDS edge capacity in k_agg
#define GM    32     // rows per MFMA gemm block
#define NBUCK 64     // partition buckets (dst >> bshift)
#define BSTR  16     // bcur stride (ints) = one 64B line per bucket
#define EPT   16     // edges per thread in k_part
#define EPB   (256 * EPT)   // 4096 edges per k_part block

typedef __attribute__((ext_vector_type(8))) short short8;   // 8 bf16 (4 VGPRs)
typedef __attribute__((ext_vector_type(4))) float f32x4;    // MFMA accumulator
typedef __attribute__((ext_vector_type(2))) float f32x2;    // fp8 cvt result

__device__ __forceinline__ float us2f(unsigned short u) {   // raw bf16 bits -> f32
    return __uint_as_float((unsigned)u << 16);
}
__device__ __forceinline__ unsigned short f2us(float v) {   // f32 -> bf16 bits (RN)
    __hip_bfloat16 hb = __float2bfloat16(v);
    return *(unsigned short*)&hb;
}
__device__ __forceinline__ unsigned char f2e4m3(float v) {  // f32 -> fp8 e4m3 (HW, OCP)
    int p = __builtin_amdgcn_cvt_pk_fp8_f32(v, 0.f, 0, false);
    return (unsigned char)(p & 0xff);
}
__device__ __forceinline__ float lrelu(float a) { return (a >= 0.f) ? a : 0.2f * a; }

// ---------------------------------------------------------------- init: deg=1 (self-loop), zero pool/cnt/bcur
__global__ void k_init0(int* __restrict__ deg, float* __restrict__ pool,
                        int* __restrict__ bcur, int N, int npool) {
    int g = blockIdx.x * blockDim.x + threadIdx.x;
    if (g < N) deg[g] = 1;
    if (g < npool) pool[g] = 0.f;
    if (g < NBUCK * BSTR) bcur[g] = 0;
}

// ---------------------------------------------------------------- 3-phase parallel exclusive scan
__global__ __launch_bounds__(256) void k_scan_a(const int* __restrict__ deg,
                                                int* __restrict__ rowptr,
                                                int* __restrict__ bsum, int N) {
    __shared__ int sh[256];
    const int t = threadIdx.x;
    const int i = blockIdx.x * 256 + t;
    int v = (i < N) ? deg[i] : 0;
    sh[t] = v;
    __syncthreads();
    #pragma unroll
    for (int o = 1; o < 256; o <<= 1) {
        int u = (t >= o) ? sh[t - o] : 0;
        __syncthreads();
        sh[t] += u;
        __syncthreads();
    }
    if (i < N) rowptr[i] = sh[t] - v;
    if (t == 255) bsum[blockIdx.x] = sh[255];
}

__global__ __launch_bounds__(256) void k_scan_b(int* __restrict__ bsum, int nb) {
    __shared__ int sh[256];
    const int t = threadIdx.x;
    int v = (t < nb) ? bsum[t] : 0;
    sh[t] = v;
    __syncthreads();
    #pragma unroll
    for (int o = 1; o < 256; o <<= 1) {
        int u = (t >= o) ? sh[t - o] : 0;
        __syncthreads();
        sh[t] += u;
        __syncthreads();
    }
    if (t < nb) bsum[t] = sh[t] - v;
}

__global__ __launch_bounds__(256) void k_scan_c(int* __restrict__ rowptr,
                                                int* __restrict__ cursor,
                                                const int* __restrict__ bsum,
                                                int N, int Etot) {
    const int i = blockIdx.x * 256 + threadIdx.x;
    if (i < N) {
        int v = rowptr[i] + bsum[blockIdx.x];
        rowptr[i] = v;
        cursor[i] = v;
    }
    if (i == 0) rowptr[N] = Etot;
}

// ---------------------------------------------------------------- CSR fill phase A: bucket partition + deg hist
// EPB=4096: 4x fewer bcur allocation round-trips; per-bucket runs ~64 entries (512B) -> clean writes
__global__ __launch_bounds__(256) void k_part(
    const int* __restrict__ ei, int E, int N, int bshift,
    unsigned long long* __restrict__ arena, int* __restrict__ bcur,
    int* __restrict__ deg, int cap)
{
    __shared__ int lhist[NBUCK];
    __shared__ int lbase[NBUCK];
    const int t = threadIdx.x;
    const int e0 = blockIdx.x * EPB;
    const int eEnd = min(e0 + EPB, E + N);

    if (t < NBUCK) lhist[t] = 0;
    __syncthreads();

    int myb[EPT], myd[EPT], mys[EPT];
    #pragma unroll
    for (int r = 0; r < EPT; ++r) {
        int e = e0 + r * 256 + t;
        myb[r] = -1;
        if (e < eEnd) {
            int s, d;
            if (e < E) { s = ei[e]; d = ei[E + e]; atomicAdd(&deg[d], 1); }
            else       { s = d = e - E; }          // self-loop: deg pre-set to 1 in init
            int b = d >> bshift;
            myb[r] = b; myd[r] = d; mys[r] = s;
            atomicAdd(&lhist[b], 1);
        }
    }
    __syncthreads();

    if (t < NBUCK) {
        int c = lhist[t];
        lbase[t] = c ? atomicAdd(&bcur[t * BSTR], c) : 0;   // one line per bucket
        lhist[t] = 0;     // reuse as local bump
    }
    __syncthreads();

    #pragma unroll
    for (int r = 0; r < EPT; ++r) {
        int b = myb[r];
        if (b >= 0) {
            int li = atomicAdd(&lhist[b], 1);
            int pos = lbase[b] + li;
            if (pos >= cap) pos = cap - 1;    // safety (statistically unreachable)
            arena[(size_t)b * cap + pos] =
                ((unsigned long long)(unsigned)myd[r] << 32) | (unsigned)mys[r];
        }
    }
}

// ---------------------------------------------------------------- CSR fill phase B: bucket-local scatter
__global__ __launch_bounds__(256) void k_fill2(
    const unsigned long long* __restrict__ arena, const int* __restrict__ bcur,
    int cap, int* __restrict__ cursor, int* __restrict__ col)
{
    const int b = blockIdx.x;
    const int idx = blockIdx.y * 256 + threadIdx.x;
    if (idx >= bcur[b * BSTR]) return;
    unsigned long long v = arena[(size_t)b * cap + idx];
    int d = (int)(v >> 32);
    int s = (int)(v & 0xffffffffu);
    int pos = atomicAdd(&cursor[d], 1);
    col[pos] = s;
}

// ---------------------------------------------------------------- prep:
// BN(x)->bf16 A; W1^T->Wt; W2^T->Wt2; folded attention mats Wast1[16][128], Wast2[16][64];
// BN1 scale/shift
__global__ __launch_bounds__(256) void k_prep(
    const float* __restrict__ x,
    const float* __restrict__ ing, const float* __restrict__ inb,
    const float* __restrict__ inm, const float* __restrict__ inv,
    const float* __restrict__ W1, const float* __restrict__ W2,
    const float* __restrict__ as1, const float* __restrict__ ad1,
    const float* __restrict__ as2, const float* __restrict__ ad2,
    const float* __restrict__ b1,
    const float* __restrict__ bn1g, const float* __restrict__ bn1b,
    const float* __restrict__ bn1m, const float* __restrict__ bn1v,
    unsigned short* __restrict__ A, unsigned short* __restrict__ Wt,
    unsigned short* __restrict__ Wt2,
    unsigned short* __restrict__ Wast1, unsigned short* __restrict__ Wast2,
    float* __restrict__ scl1, float* __restrict__ shf1, int N)
{
    int g = blockIdx.x * blockDim.x + threadIdx.x;
    int totA = N * (DIN / 4);
    if (g < totA) {
        int n = g >> 5, k4 = (g & 31) * 4;
        float4 xv = *(const float4*)(x + (size_t)n * DIN + k4);
        float4 gm = *(const float4*)(ing + k4);
        float4 bb = *(const float4*)(inb + k4);
        float4 mm = *(const float4*)(inm + k4);
        float4 vv = *(const float4*)(inv + k4);
        ushort4 o;
        o.x = f2us((xv.x - mm.x) * rsqrtf(vv.x + EPS) * gm.x + bb.x);
        o.y = f2us((xv.y - mm.y) * rsqrtf(vv.y + EPS) * gm.y + bb.y);
        o.z = f2us((xv.z - mm.z) * rsqrtf(vv.z + EPS) * gm.z + bb.z);
        o.w = f2us((xv.w - mm.w) * rsqrtf(vv.w + EPS) * gm.w + bb.w);
        *(ushort4*)(A + (size_t)n * DIN + k4) = o;
    }
    if (g < 256 * DIN) {   // Wt[n][k] = W1[k][n]
        int n = g >> 7, k = g & 127;
        Wt[g] = f2us(W1[(size_t)k * 256 + n]);
    }
    if (g < 256 * DHID) {  // Wt2[n][k] = W2[k][n]
        int n = g >> 6, k = g & 63;
        Wt2[g] = f2us(W2[(size_t)k * 256 + n]);
    }
    if (g < 16 * DIN) {    // Wast1[c][k]: c<4 -> W1·as1 head c ; 4..7 -> W1·ad1 ; 8..15 -> 0
        int c = g >> 7, k = g & 127;
        float s = 0.f;
        if (c < 4)      { for (int j = 0; j < 64; ++j) s += W1[(size_t)k * 256 + c * 64 + j] * as1[c * 64 + j]; }
        else if (c < 8) { for (int j = 0; j < 64; ++j) s += W1[(size_t)k * 256 + (c - 4) * 64 + j] * ad1[(c - 4) * 64 + j]; }
        Wast1[g] = f2us(s);
    }
    if (g < 16 * DHID) {   // Wast2[c][k]
        int c = g >> 6, k = g & 63;
        float s = 0.f;
        if (c < 4)      { for (int j = 0; j < 64; ++j) s += W2[(size_t)k * 256 + c * 64 + j] * as2[c * 64 + j]; }
        else if (c < 8) { for (int j = 0; j < 64; ++j) s += W2[(size_t)k * 256 + (c - 4) * 64 + j] * ad2[(c - 4) * 64 + j]; }
        Wast2[g] = f2us(s);
    }
    if (g < DHID) {        // fold b1 + BN1 into scale/shift
        float sc = bn1g[g] * rsqrtf(bn1v[g] + EPS);
        scl1[g] = sc;
        shf1[g] = (b1[g] - bn1m[g]) * sc + bn1b[g];
    }
}

// ---------------------------------------------------------------- layer-1 GEMM via MFMA (h fp8 + fused att)
__global__ __launch_bounds__(256) void k_gemm1(
    const unsigned short* __restrict__ A,    // [N][128] bf16
    const unsigned short* __restrict__ Wt,   // [256][128] bf16
    const unsigned short* __restrict__ Wast, // [16][128] bf16 (cols 8..15 zero)
    unsigned char* __restrict__ h,           // [N][256] fp8 (transposed [n][c][hd])
    float* __restrict__ asrc, float* __restrict__ adst, int N)
{
    __shared__ float Csh[GM][260];
    const int t = threadIdx.x;
    const int lane = t & 63, wv = t >> 6;
    const int qm = lane & 15, qd = lane >> 4;
    const int base = blockIdx.x * GM;

    short8 afr[2][4];
    #pragma unroll
    for (int rt = 0; rt < 2; ++rt) {
        int node = base + rt * 16 + qm;
        if (node >= N) node = N - 1;
        const unsigned short* ap = A + (size_t)node * DIN + qd * 8;
        #pragma unroll
        for (int ks = 0; ks < 4; ++ks)
            afr[rt][ks] = *(const short8*)(ap + ks * 32);
    }

    const int n0 = wv * 64;
    f32x4 acc[2][4];
    #pragma unroll
    for (int rt = 0; rt < 2; ++rt)
        #pragma unroll
        for (int ct = 0; ct < 4; ++ct)
            acc[rt][ct] = (f32x4){0.f, 0.f, 0.f, 0.f};

    #pragma unroll
    for (int ct = 0; ct < 4; ++ct) {
        const unsigned short* bp = Wt + (size_t)(n0 + ct * 16 + qm) * DIN + qd * 8;
        #pragma unroll
        for (int ks = 0; ks < 4; ++ks) {
            short8 bfr = *(const short8*)(bp + ks * 32);
            acc[0][ct] = __builtin_amdgcn_mfma_f32_16x16x32_bf16(afr[0][ks], bfr, acc[0][ct], 0, 0, 0);
            acc[1][ct] = __builtin_amdgcn_mfma_f32_16x16x32_bf16(afr[1][ks], bfr, acc[1][ct], 0, 0, 0);
        }
    }

    // fused attention logits: [asrc|adst] = A @ Wast^T (reuses afr)
    {
        const unsigned short* wp = Wast + (size_t)qm * DIN + qd * 8;
        f32x4 aat[2];
        aat[0] = (f32x4){0.f, 0.f, 0.f, 0.f};
        aat[1] = (f32x4){0.f, 0.f, 0.f, 0.f};
        #pragma unroll
        for (int ks = 0; ks < 4; ++ks) {
            short8 wfr = *(const short8*)(wp + ks * 32);
            aat[0] = __builtin_amdgcn_mfma_f32_16x16x32_bf16(afr[0][ks], wfr, aat[0], 0, 0, 0);
            aat[1] = __builtin_amdgcn_mfma_f32_16x16x32_bf16(afr[1][ks], wfr, aat[1], 0, 0, 0);
        }
        const int c = qm;   // C layout: col = lane&15, row = qd*4+rg
        #pragma unroll
        for (int rt = 0; rt < 2; ++rt)
            #pragma unroll
            for (int rg = 0; rg < 4; ++rg) {
                int nd = base + rt * 16 + qd * 4 + rg;
                if (nd < N) {
                    if (c < 4)      asrc[nd * 4 + c] = aat[rt][rg];
                    else if (c < 8) adst[nd * 4 + (c - 4)] = aat[rt][rg];
                }
            }
    }

    #pragma unroll
    for (int rt = 0; rt < 2; ++rt)
        #pragma unroll
        for (int ct = 0; ct < 4; ++ct)
            #pragma unroll
            for (int rg = 0; rg < 4; ++rg)
                Csh[rt * 16 + qd * 4 + rg][n0 + ct * 16 + qm] = acc[rt][ct][rg];
    __syncthreads();

    const int hcol = ((t & 3) << 6) | (t >> 2);   // h[n][t] <- C[n][(t&3)*64 + (t>>2)]
    for (int r = 0; r < GM; ++r) {
        int node = base + r;
        if (node >= N) break;
        h[(size_t)node * 256 + t] = f2e4m3(Csh[r][hcol]);
    }
}

// ---------------------------------------------------------------- layer-2 GEMM via MFMA (K=64, h fp8 + fused att)
__global__ __launch_bounds__(256) void k_gemm2(
    const unsigned short* __restrict__ A2,   // [N][64] bf16
    const unsigned short* __restrict__ Wt2,  // [256][64] bf16
    const unsigned short* __restrict__ Wast, // [16][64] bf16
    unsigned char* __restrict__ h,
    float* __restrict__ asrc, float* __restrict__ adst, int N)
{
    __shared__ float Csh[GM][260];
    const int t = threadIdx.x;
    const int lane = t & 63, wv = t >> 6;
    const int qm = lane & 15, qd = lane >> 4;
    const int base = blockIdx.x * GM;

    short8 afr[2][2];
    #pragma unroll
    for (int rt = 0; rt < 2; ++rt) {
        int node = base + rt * 16 + qm;
        if (node >= N) node = N - 1;
        const unsigned short* ap = A2 + (size_t)node * DHID + qd * 8;
        #pragma unroll
        for (int ks = 0; ks < 2; ++ks)
            afr[rt][ks] = *(const short8*)(ap + ks * 32);
    }

    const int n0 = wv * 64;
    f32x4 acc[2][4];
    #pragma unroll
    for (int rt = 0; rt < 2; ++rt)
        #pragma unroll
        for (int ct = 0; ct < 4; ++ct)
            acc[rt][ct] = (f32x4){0.f, 0.f, 0.f, 0.f};

    #pragma unroll
    for (int ct = 0; ct < 4; ++ct) {
        const unsigned short* bp = Wt2 + (size_t)(n0 + ct * 16 + qm) * DHID + qd * 8;
        #pragma unroll
        for (int ks = 0; ks < 2; ++ks) {
            short8 bfr = *(const short8*)(bp + ks * 32);
            acc[0][ct] = __builtin_amdgcn_mfma_f32_16x16x32_bf16(afr[0][ks], bfr, acc[0][ct], 0, 0, 0);
            acc[1][ct] = __builtin_amdgcn_mfma_f32_16x16x32_bf16(afr[1][ks], bfr, acc[1][ct], 0, 0, 0);
        }
    }

    // fused attention logits
    {
        const unsigned short* wp = Wast + (size_t)qm * DHID + qd * 8;
        f32x4 aat[2];
        aat[0] = (f32x4){0.f, 0.f, 0.f, 0.f};
        aat[1] = (f32x4){0.f, 0.f, 0.f, 0.f};
        #pragma unroll
        for (int ks = 0; ks < 2; ++ks) {
            short8 wfr = *(const short8*)(wp + ks * 32);
            aat[0] = __builtin_amdgcn_mfma_f32_16x16x32_bf16(afr[0][ks], wfr, aat[0], 0, 0, 0);
            aat[1] = __builtin_amdgcn_mfma_f32_16x16x32_bf16(afr[1][ks], wfr, aat[1], 0, 0, 0);
        }
        const int c = qm;
        #pragma unroll
        for (int rt = 0; rt < 2; ++rt)
            #pragma unroll
            for (int rg = 0; rg < 4; ++rg) {
                int nd = base + rt * 16 + qd * 4 + rg;
                if (nd < N) {
                    if (c < 4)      asrc[nd * 4 + c] = aat[rt][rg];
                    else if (c < 8) adst[nd * 4 + (c - 4)] = aat[rt][rg];
                }
            }
    }

    #pragma unroll
    for (int rt = 0; rt < 2; ++rt)
        #pragma unroll
        for (int ct = 0; ct < 4; ++ct)
            #pragma unroll
            for (int rg = 0; rg < 4; ++rg)
                Csh[rt * 16 + qd * 4 + rg][n0 + ct * 16 + qm] = acc[rt][ct][rg];
    __syncthreads();

    const int hcol = ((t & 3) << 6) | (t >> 2);
    for (int r = 0; r < GM; ++r) {
        int node = base + r;
        if (node >= N) break;
        h[(size_t)node * 256 + t] = f2e4m3(Csh[r][hcol]);
    }
}

// ---------------------------------------------------------------- pull-style GAT aggregation (fp8 h)
__global__ __launch_bounds__(256) void k_agg(
    const int* __restrict__ rowptr, const int* __restrict__ col,
    const float* __restrict__ asrc, const float* __restrict__ adst,
    const unsigned char* __restrict__ h8,
    float* __restrict__ outf, unsigned short* __restrict__ outb,
    const float* __restrict__ scl, const float* __restrict__ shf,
    int mode, int N)
{
    __shared__ float4 exs[4][CAP];
    __shared__ int    cols[4][CAP];
    const int lane = threadIdx.x & 63;
    const int wv   = threadIdx.x >> 6;
    const int d = (blockIdx.x << 2) + wv;
    if (d >= N) return;
    const int r0  = rowptr[d];
    const int deg = rowptr[d + 1] - r0;        // >= 1 (self-loop)

    const float4 ad4 = ((const float4*)adst)[d];
    const float4* __restrict__ as4 = (const float4*)asrc;

    // pass A: exp(lrelu(logit)) -> LDS, per-head sum
    float sm0 = 0.f, sm1 = 0.f, sm2 = 0.f, sm3 = 0.f;
    for (int j = lane; j < deg; j += 64) {
        int s = col[r0 + j];
        float4 a = as4[s];
        float e0 = __expf(lrelu(a.x + ad4.x));
        float e1 = __expf(lrelu(a.y + ad4.y));
        float e2 = __expf(lrelu(a.z + ad4.z));
        float e3 = __expf(lrelu(a.w + ad4.w));
        if (j < CAP) { cols[wv][j] = s; exs[wv][j] = make_float4(e0, e1, e2, e3); }
        sm0 += e0; sm1 += e1; sm2 += e2; sm3 += e3;
    }
    #pragma unroll
    for (int o = 1; o < 64; o <<= 1) {
        sm0 += __shfl_xor(sm0, o, 64);
        sm1 += __shfl_xor(sm1, o, 64);
        sm2 += __shfl_xor(sm2, o, 64);
        sm3 += __shfl_xor(sm3, o, 64);
    }
    const float i0 = 0.25f / sm0, i1 = 0.25f / sm1, i2 = 0.25f / sm2, i3 = 0.25f / sm3;

    // pass B: lane = channel; 4 independent dword gathers per iteration
    const unsigned int* __restrict__ hu = (const unsigned int*)h8;
    float a0 = 0.f, a1 = 0.f, a2 = 0.f, a3 = 0.f;
    float b0 = 0.f, b1 = 0.f, b2 = 0.f, b3 = 0.f;
    if (deg <= CAP) {
        int j = 0;
        for (; j + 3 < deg; j += 4) {
            int sA = cols[wv][j],     sB = cols[wv][j + 1];
            int sC = cols[wv][j + 2], sD = cols[wv][j + 3];
            unsigned int vA = hu[(size_t)sA * 64 + lane];
            unsigned int vB = hu[(size_t)sB * 64 + lane];
            unsigned int vC = hu[(size_t)sC * 64 + lane];
            unsigned int vD = hu[(size_t)sD * 64 + lane];
            float4 wA = exs[wv][j],     wB = exs[wv][j + 1];
            float4 wC = exs[wv][j + 2], wD = exs[wv][j + 3];
            f32x2 lA = __builtin_amdgcn_cvt_pk_f32_fp8(vA, false), hA = __builtin_amdgcn_cvt_pk_f32_fp8(vA, true);
            f32x2 lB = __builtin_amdgcn_cvt_pk_f32_fp8(vB, false), hB = __builtin_amdgcn_cvt_pk_f32_fp8(vB, true);
            f32x2 lC = __builtin_amdgcn_cvt_pk_f32_fp8(vC, false), hC = __builtin_amdgcn_cvt_pk_f32_fp8(vC, true);
            f32x2 lD = __builtin_amdgcn_cvt_pk_f32_fp8(vD, false), hD = __builtin_amdgcn_cvt_pk_f32_fp8(vD, true);
            a0 += wA.x * lA.x; a1 += wA.y * lA.y; a2 += wA.z * hA.x; a3 += wA.w * hA.y;
            b0 += wB.x * lB.x; b1 += wB.y * lB.y; b2 += wB.z * hB.x; b3 += wB.w * hB.y;
            a0 += wC.x * lC.x; a1 += wC.y * lC.y; a2 += wC.z * hC.x; a3 += wC.w * hC.y;
            b0 += wD.x * lD.x; b1 += wD.y * lD.y; b2 += wD.z * hD.x; b3 += wD.w * hD.y;
        }
        for (; j < deg; ++j) {
            int s = cols[wv][j];
            unsigned int v = hu[(size_t)s * 64 + lane];
            float4 w = exs[wv][j];
            f32x2 lo = __builtin_amdgcn_cvt_pk_f32_fp8(v, false), hi = __builtin_amdgcn_cvt_pk_f32_fp8(v, true);
            a0 += w.x * lo.x; a1 += w.y * lo.y; a2 += w.z * hi.x; a3 += w.w * hi.y;
        }
    } else {                                     // rare: deg > CAP, recompute weights
        for (int j = 0; j < deg; ++j) {
            int s; float4 w;
            if (j < CAP) { s = cols[wv][j]; w = exs[wv][j]; }
            else {
                s = col[r0 + j];
                float4 a = as4[s];
                w.x = __expf(lrelu(a.x + ad4.x)); w.y = __expf(lrelu(a.y + ad4.y));
                w.z = __expf(lrelu(a.z + ad4.z)); w.w = __expf(lrelu(a.w + ad4.w));
            }
            unsigned int v = hu[(size_t)s * 64 + lane];
            f32x2 lo = __builtin_amdgcn_cvt_pk_f32_fp8(v, false), hi = __builtin_amdgcn_cvt_pk_f32_fp8(v, true);
            a0 += w.x * lo.x; a1 += w.y * lo.y; a2 += w.z * hi.x; a3 += w.w * hi.y;
        }
    }
    float acc = (a0 + b0) * i0 + (a1 + b1) * i1 + (a2 + b2) * i2 + (a3 + b3) * i3;

    if (mode) {
        float v = fmaxf(acc * scl[lane] + shf[lane], 0.f);
        outb[(size_t)d * 64 + lane] = f2us(v);
    } else {
        outf[(size_t)d * 64 + lane] = acc;
    }
}

// ---------------------------------------------------------------- pool (unchanged)
__global__ __launch_bounds__(256) void k_pool(
    const float* __restrict__ outacc,
    const float* __restrict__ b2_,
    const float* __restrict__ bg, const float* __restrict__ bb,
    const float* __restrict__ bm, const float* __restrict__ bv,
    const int* __restrict__ batch,
    float* __restrict__ pool, float* __restrict__ cnt, int N)
{
    const int lane = threadIdx.x & 63;
    const int wave = threadIdx.x >> 6;
    const int base = blockIdx.x * PNODES;
    int end = base + PNODES; if (end > N) end = N;

    const float scale = bg[lane] * rsqrtf(bv[lane] + EPS);
    const float shift = (b2_[lane] - bm[lane]) * scale + bb[lane];

    float acc = 0.f;
    int cur = -1, cl = 0;
    for (int n = base + wave; n < end; n += 4) {
        int gr = batch[n];
        if (gr != cur) {
            if (cur >= 0) {
                atomicAdd(&pool[cur * 64 + lane], acc);
                if (lane == 0) atomicAdd(&cnt[cur], (float)cl);
            }
            cur = gr; acc = 0.f; cl = 0;
        }
        float v = fmaxf(outacc[(size_t)n * 64 + lane] * scale + shift, 0.f);
        acc += v; ++cl;
    }
    if (cur >= 0) {
        atomicAdd(&pool[cur * 64 + lane], acc);
        if (lane == 0) atomicAdd(&cnt[cur], (float)cl);
    }
}

// ---------------------------------------------------------------- head (unchanged)
__global__ void k_head(const float* __restrict__ pool, const float* __restrict__ cnt,
                       const float* __restrict__ fc1w, const float* __restrict__ fc1b,
                       const float* __restrict__ fc2w, const float* __restrict__ fc2b,
                       float* __restrict__ out)
{
    int g = blockIdx.x;
    int t = threadIdx.x;  // 64 threads
    __shared__ float emb[64];
    __shared__ float z1[32];
    float c = fmaxf(cnt[g], 1.0f);
    emb[t] = pool[g * 64 + t] / c;
    __syncthreads();
    if (t < 32) {
        float s = fc1b[t];
        for (int k = 0; k < 64; ++k) s += emb[k] * fc1w[k * 32 + t];
        z1[t] = fmaxf(s, 0.f);
    }
    __syncthreads();
    if (t < 32) {
        float o = fc2b[t];
        for (int j = 0; j < 32; ++j) o += z1[j] * fc2w[j * 32 + t];
        out[g * 32 + t] = o;
    }
}

// ---------------------------------------------------------------- launch
extern "C" void kernel_launch(void* const* d_in, const int* in_sizes, int n_in,
                              void* d_out, int out_size, void* d_ws, size_t ws_size,
                              hipStream_t stream)
{
    const float* x    = (const float*)d_in[0];
    const int*   ei   = (const int*)d_in[1];
    const int*   batch= (const int*)d_in[2];
    const float* ing  = (const float*)d_in[3];
    const float* inb  = (const float*)d_in[4];
    const float* inm  = (const float*)d_in[5];
    const float* inv  = (const float*)d_in[6];
    const float* W1   = (const float*)d_in[7];
    const float* as1  = (const float*)d_in[8];
    const float* ad1  = (const float*)d_in[9];
    const float* b1   = (const float*)d_in[10];
    const float* bn1g = (const float*)d_in[11];
    const float* bn1b = (const float*)d_in[12];
    const float* bn1m = (const float*)d_in[13];
    const float* bn1v = (const float*)d_in[14];
    const float* W2   = (const float*)d_in[15];
    const float* as2  = (const float*)d_in[16];
    const float* ad2  = (const float*)d_in[17];
    const float* b2   = (const float*)d_in[18];
    const float* bn2g = (const float*)d_in[19];
    const float* bn2b = (const float*)d_in[20];
    const float* bn2m = (const float*)d_in[21];
    const float* bn2v = (const float*)d_in[22];
    const float* fc1w = (const float*)d_in[23];
    const float* fc1b = (const float*)d_in[24];
    const float* fc2w = (const float*)d_in[25];
    const float* fc2b = (const float*)d_in[26];

    const int N = in_sizes[0] / DIN;
    const int E = in_sizes[1] / 2;
    const int G = out_size / DOUT;
    const int Etot = E + N;

    // bucket shift: smallest with (N-1)>>bshift < NBUCK
    int bshift = 0;
    while ((N >> bshift) >= NBUCK) ++bshift;
    // per-bucket arena capacity: expected density * 1.25 + slack
    const int cap = (int)(((long long)Etot << bshift) / N * 5 / 4) + 512;

    // workspace layout — ~43 MB
    unsigned char* h8 = (unsigned char*)d_ws;             // N*256 fp8 (transposed [n][c][hd])
    float* asrc   = (float*)(h8 + (size_t)N * 256);       // N*4
    float* adst   = asrc + (size_t)N * NH;                // N*4
    unsigned short* Wt    = (unsigned short*)(adst + (size_t)N * NH); // 256*128
    unsigned short* Wt2   = Wt + 256 * DIN;               // 256*64
    unsigned short* Wast1 = Wt2 + 256 * DHID;             // 16*128
    unsigned short* Wast2 = Wast1 + 16 * DIN;             // 16*64
    float* scl1   = (float*)(Wast2 + 16 * DHID);          // 64
    float* shf1   = scl1 + DHID;                          // 64
    float* outacc = shf1 + DHID;                          // N*64 f32
    unsigned short* A  = (unsigned short*)outacc;         // alias: N*128 bf16 (dead after gemm1)
    unsigned short* A2 = (unsigned short*)outacc;         // alias: N*64 bf16 (layer-1 agg out)
    int*   deg    = (int*)(outacc + (size_t)N * DHID);    // N
    int*   rowptr = deg + N;                              // N+1
    int*   cursor = rowptr + N + 1;                       // N
    int*   col    = cursor + N;                           // E+N
    float* pool   = (float*)(col + Etot);                 // G*64
    float* cnt    = pool + (size_t)G * DHID;              // G
    int*   bsum   = (int*)(cnt + G);                      // <=256
    int*   bcur   = (int*)(((size_t)(bsum + 256) + 63) & ~(size_t)63); // NBUCK*BSTR (line-padded)
    unsigned long long* arena =
        (unsigned long long*)(((size_t)(bcur + NBUCK * BSTR) + 7) & ~(size_t)7); // NBUCK*cap*8B

    const int npool = G * DHID + G;
    const int nScanBlk = (N + 255) / 256;
    dim3 b256(256);

    // ---- CSR build (deg-hist fused into k_part) + zero pool/cnt/bcur
    k_init0<<<(N + 255) / 256, b256, 0, stream>>>(deg, pool, bcur, N, npool);
    k_part<<<(Etot + EPB - 1) / EPB, b256, 0, stream>>>(ei, E, N, bshift, arena, bcur, deg, cap);
    k_scan_a<<<nScanBlk, b256, 0, stream>>>(deg, rowptr, bsum, N);
    k_scan_b<<<1, b256, 0, stream>>>(bsum, nScanBlk);
    k_scan_c<<<nScanBlk, b256, 0, stream>>>(rowptr, cursor, bsum, N, Etot);
    {
        dim3 gFill(NBUCK, (cap + 255) / 256);
        k_fill2<<<gFill, b256, 0, stream>>>(arena, bcur, cap, cursor, col);
    }

    // ---- prep (BN+cast x, transpose W1/W2, fold attention mats, BN1 fold)
    const int prepThreads = N * (DIN / 4);
    k_prep<<<(prepThreads + 255) / 256, b256, 0, stream>>>(
        x, ing, inb, inm, inv, W1, W2, as1, ad1, as2, ad2,
        b1, bn1g, bn1b, bn1m, bn1v,
        A, Wt, Wt2, Wast1, Wast2, scl1, shf1, N);

    // ---- layer 1 (MFMA, fused att); agg writes bf16 A2 (bias+BN1+ReLU fused)
    k_gemm1<<<(N + GM - 1) / GM, b256, 0, stream>>>(A, Wt, Wast1, h8, asrc, adst, N);
    k_agg<<<(N + 3) / 4, b256, 0, stream>>>(rowptr, col, asrc, adst, h8,
                                            (float*)nullptr, A2, scl1, shf1, 1, N);

    // ---- layer 2 (MFMA, fused att); agg writes raw f32 for pool
    k_gemm2<<<(N + GM - 1) / GM, b256, 0, stream>>>(A2, Wt2, Wast2, h8, asrc, adst, N);
    k_agg<<<(N + 3) / 4, b256, 0, stream>>>(rowptr, col, asrc, adst, h8,
                                            outacc, (unsigned short*)nullptr,
                                            (const float*)nullptr, (const float*)nullptr, 0, N);

    // ---- pool + head
    k_pool<<<(N + PNODES - 1) / PNODES, b256, 0, stream>>>(outacc, b2, bn2g, bn2b, bn2m, bn2v,
                                                           batch, pool, cnt, N);
    k_head<<<G, 64, 0, stream>>>(pool, cnt, fc1w, fc1b, fc2w, fc2b, (float*)d_out);
}